// Round 7
// baseline (3882.093 us; speedup 1.0000x reference)
//
#include <hip/hip_runtime.h>

typedef unsigned long long ull;

constexpr int KK = 3;
constexpr int SRC_BITS = 10;               // src bucket = 1024 nodes
constexpr int SRC_BUCK = 1 << SRC_BITS;
constexpr int DST_BITS = 12;               // dst bucket = 4096 nodes (primary)
constexpr int DST_BUCK = 1 << DST_BITS;
constexpr int NPB_A = 64;                  // partition-A blocks (977 open streams -> keep tiny)
constexpr int NPB_B = 128;                 // partition-B blocks (245 open streams)
constexpr int PBT = 1024;                  // partition threads/block

__device__ __forceinline__ float relu_(float v) { return fmaxf(v, 0.f); }

// =================== generic helpers ===================

template <int NT>
__global__ void colscan_kernel(int* __restrict__ bh, int* __restrict__ total, int nb) {
    __shared__ int sm[NT];
    int i = blockIdx.x, tid = threadIdx.x;
    int v = bh[(size_t)tid * nb + i];
    sm[tid] = v;
    __syncthreads();
    for (int off = 1; off < NT; off <<= 1) {
        int t = (tid >= off) ? sm[tid - off] : 0;
        __syncthreads();
        sm[tid] += t;
        __syncthreads();
    }
    bh[(size_t)tid * nb + i] = sm[tid] - v;    // exclusive over blocks
    if (tid == NT - 1) total[i] = sm[tid];
}

// single-block exclusive scan (nb <= 1024), writes sentinel base[nb] = E
__global__ void excl_scan_kernel(const int* __restrict__ total, int* __restrict__ base,
                                 int nb, int E) {
    __shared__ int sm[1024];
    int tid = threadIdx.x;
    int v = (tid < nb) ? total[tid] : 0;
    sm[tid] = v;
    __syncthreads();
    for (int off = 1; off < 1024; off <<= 1) {
        int t = (tid >= off) ? sm[tid - off] : 0;
        __syncthreads();
        sm[tid] += t;
        __syncthreads();
    }
    if (tid < nb) base[tid] = sm[tid] - v;
    if (tid == 0) base[nb] = E;
}

// =================== primary build: src-partition then dst-partition ===================

// hist by src bucket (row >> SRC_BITS); grid = NPB_A
__global__ void histA_kernel(const int* __restrict__ row, int* __restrict__ bh, int E, int nb) {
    __shared__ int h[1024];
    for (int i = threadIdx.x; i < nb; i += blockDim.x) h[i] = 0;
    __syncthreads();
    long e0 = (long)blockIdx.x * E / gridDim.x;
    long e1 = (long)(blockIdx.x + 1) * E / gridDim.x;
    for (long e = e0 + threadIdx.x; e < e1; e += blockDim.x)
        atomicAdd(&h[__builtin_nontemporal_load(row + e) >> SRC_BITS], 1);
    __syncthreads();
    int* dst = bh + (size_t)blockIdx.x * nb;
    for (int i = threadIdx.x; i < nb; i += blockDim.x) dst[i] = h[i];
}

// partition by src bucket: tmpA[pos] = { (dst<<10) | src_low , w_bits }
__global__ void partA_kernel(const int* __restrict__ row, const int* __restrict__ col,
                             const float* __restrict__ w, const int* __restrict__ cBaseA,
                             const int* __restrict__ bhA, uint2* __restrict__ tmpA,
                             int E, int nbA) {
    __shared__ int cur[1024];
    const int* boff = bhA + (size_t)blockIdx.x * nbA;
    for (int i = threadIdx.x; i < nbA; i += blockDim.x) cur[i] = cBaseA[i] + boff[i];
    __syncthreads();
    long e0 = (long)blockIdx.x * E / gridDim.x;
    long e1 = (long)(blockIdx.x + 1) * E / gridDim.x;
    for (long e = e0 + threadIdx.x; e < e1; e += blockDim.x) {
        int r = __builtin_nontemporal_load(row + e);
        int c = __builtin_nontemporal_load(col + e);
        float wv = __builtin_nontemporal_load(w + e);
        int b = r >> SRC_BITS;
        int pos = atomicAdd(&cur[b], 1);
        uint2 t;
        t.x = ((unsigned)c << SRC_BITS) | (unsigned)(r & (SRC_BUCK - 1));
        t.y = __float_as_uint(wv);
        tmpA[pos] = t;
    }
}

// hist of tmpA by dst bucket (keyA >> 22); grid = NPB_B
__global__ void histB_kernel(const uint2* __restrict__ tmpA, int* __restrict__ bh,
                             int E, int nb) {
    __shared__ int h[1024];
    for (int i = threadIdx.x; i < nb; i += blockDim.x) h[i] = 0;
    __syncthreads();
    const ull* tp = (const ull*)tmpA;
    long e0 = (long)blockIdx.x * E / gridDim.x;
    long e1 = (long)(blockIdx.x + 1) * E / gridDim.x;
    for (long e = e0 + threadIdx.x; e < e1; e += blockDim.x) {
        ull v = __builtin_nontemporal_load(tp + e);
        atomicAdd(&h[((unsigned)v) >> (SRC_BITS + DST_BITS)], 1);
    }
    __syncthreads();
    int* dst = bh + (size_t)blockIdx.x * nb;
    for (int i = threadIdx.x; i < nb; i += blockDim.x) dst[i] = h[i];
}

// partition tmpA -> tmpB by dst bucket, reconstructing full src from position.
// tmpB[pos] = { (dst_low<<20) | src_full , w_bits }
__global__ void partB_kernel(const uint2* __restrict__ tmpA, const int* __restrict__ cBaseA,
                             const int* __restrict__ cBaseB, const int* __restrict__ bhB,
                             uint2* __restrict__ tmpB, int E, int nbA, int nbB) {
    __shared__ int cur[1024];
    __shared__ int sA[1025];
    const int* boff = bhB + (size_t)blockIdx.x * nbB;
    for (int i = threadIdx.x; i < nbB; i += blockDim.x) cur[i] = cBaseB[i] + boff[i];
    for (int i = threadIdx.x; i <= nbA; i += blockDim.x) sA[i] = cBaseA[i];
    __syncthreads();
    long e0 = (long)blockIdx.x * E / gridDim.x;
    long e1 = (long)(blockIdx.x + 1) * E / gridDim.x;
    const ull* tp = (const ull*)tmpA;
    long j = e0 + threadIdx.x;
    int p = 0;
    if (j < e1) {                               // binary-search initial src bucket
        int lo = 0, hi = nbA;
        while (lo + 1 < hi) { int m = (lo + hi) >> 1; if ((long)sA[m] <= j) lo = m; else hi = m; }
        p = lo;
    }
    for (; j < e1; j += blockDim.x) {
        while (j >= (long)sA[p + 1]) ++p;       // monotone walk
        ull v = __builtin_nontemporal_load(tp + j);
        unsigned key = (unsigned)v;
        unsigned dst = key >> SRC_BITS;         // 20 bits
        unsigned srcf = ((unsigned)p << SRC_BITS) | (key & (SRC_BUCK - 1));
        int b = dst >> DST_BITS;
        int pos = atomicAdd(&cur[b], 1);
        uint2 t;
        t.x = ((dst & (DST_BUCK - 1)) << 20) | srcf;
        t.y = (unsigned)(v >> 32);
        tmpB[pos] = t;
    }
}

// =================== fallback build: direct dst partition (1024-node buckets) ===================

__global__ void histD_kernel(const int* __restrict__ col, int* __restrict__ bh, int E, int nb) {
    __shared__ int h[1024];
    for (int i = threadIdx.x; i < nb; i += blockDim.x) h[i] = 0;
    __syncthreads();
    long e0 = (long)blockIdx.x * E / gridDim.x;
    long e1 = (long)(blockIdx.x + 1) * E / gridDim.x;
    for (long e = e0 + threadIdx.x; e < e1; e += blockDim.x)
        atomicAdd(&h[__builtin_nontemporal_load(col + e) >> SRC_BITS], 1);
    __syncthreads();
    int* dst = bh + (size_t)blockIdx.x * nb;
    for (int i = threadIdx.x; i < nb; i += blockDim.x) dst[i] = h[i];
}

__global__ void partD_kernel(const int* __restrict__ row, const int* __restrict__ col,
                             const float* __restrict__ w, const int* __restrict__ cBase,
                             const int* __restrict__ bhD, uint2* __restrict__ tmp,
                             int E, int nb) {
    __shared__ int cur[1024];
    const int* boff = bhD + (size_t)blockIdx.x * nb;
    for (int i = threadIdx.x; i < nb; i += blockDim.x) cur[i] = cBase[i] + boff[i];
    __syncthreads();
    long e0 = (long)blockIdx.x * E / gridDim.x;
    long e1 = (long)(blockIdx.x + 1) * E / gridDim.x;
    for (long e = e0 + threadIdx.x; e < e1; e += blockDim.x) {
        int c = __builtin_nontemporal_load(col + e);
        int r = __builtin_nontemporal_load(row + e);
        float wv = __builtin_nontemporal_load(w + e);
        int b = c >> SRC_BITS;
        int pos = atomicAdd(&cur[b], 1);
        uint2 t;
        t.x = ((unsigned)(c & (SRC_BUCK - 1)) << 20) | (unsigned)r;
        t.y = __float_as_uint(wv);
        tmp[pos] = t;
    }
}

// =================== bucket-stream compute (templated on dst-bucket size) ===================
// tmp entry: { (cl<<20) | src , w_bits }, cl = node & (DB-1), node = (blockIdx<<DBITS)+cl

template <int DBITS>
__global__ void bucket_deg_t(const uint2* __restrict__ tmp, const int* __restrict__ cBase,
                             const float* __restrict__ x, float* __restrict__ dinv,
                             float* __restrict__ xd, int N) {
    constexpr int DB = 1 << DBITS;
    __shared__ float ws[DB];
    int bk = blockIdx.x, tid = threadIdx.x;
    for (int i = tid; i < DB; i += blockDim.x) ws[i] = 0.f;
    __syncthreads();
    long beg = cBase[bk], end = cBase[bk + 1];
    const ull* tp = (const ull*)tmp;
    for (long j = beg + tid; j < end; j += blockDim.x) {
        ull v = __builtin_nontemporal_load(tp + j);
        atomicAdd(&ws[((unsigned)v) >> 20], __uint_as_float((unsigned)(v >> 32)));
    }
    __syncthreads();
    for (int q = tid; q < DB; q += blockDim.x) {
        int node = (bk << DBITS) + q;
        if (node < N) {
            float s = ws[q];
            float di = (s > 0.f) ? rsqrtf(s) : 0.f;
            dinv[node] = di;
            xd[node] = di * x[node];
        }
    }
}

template <int DBITS>
__global__ void layer0_t(const uint2* __restrict__ tmp, const int* __restrict__ cBase,
                         const float* __restrict__ xd, const float* __restrict__ x,
                         const float* __restrict__ dinv, const float* __restrict__ W,
                         const float* __restrict__ V, const float* __restrict__ b,
                         float* __restrict__ zd0, float* __restrict__ zd1,
                         float* __restrict__ zd2, int N) {
    constexpr int DB = 1 << DBITS;
    __shared__ float acc[DB];
    int bk = blockIdx.x, tid = threadIdx.x;
    for (int i = tid; i < DB; i += blockDim.x) acc[i] = 0.f;
    __syncthreads();
    long beg = cBase[bk], end = cBase[bk + 1];
    const ull* tp = (const ull*)tmp;
    for (long j = beg + tid; j < end; j += blockDim.x) {
        ull v = __builtin_nontemporal_load(tp + j);
        unsigned key = (unsigned)v;
        atomicAdd(&acc[key >> 20], __uint_as_float((unsigned)(v >> 32)) * xd[key & 0xFFFFF]);
    }
    __syncthreads();
    float W0 = W[0], W1 = W[1], W2 = W[2];
    float V0 = V[0], V1 = V[1], V2 = V[2];
    float b0 = b[0], b1 = b[1], b2 = b[2];
    for (int q = tid; q < DB; q += blockDim.x) {
        int node = (bk << DBITS) + q;
        if (node < N) {
            float di = dinv[node];
            float s = di * acc[q];
            float xi = x[node];
            zd0[node] = di * relu_(fmaf(W0, s, fmaf(V0, xi, b0)));
            zd1[node] = di * relu_(fmaf(W1, s, fmaf(V1, xi, b1)));
            zd2[node] = di * relu_(fmaf(W2, s, fmaf(V2, xi, b2)));
        }
    }
}

// MODE 0: zd_out = dinv*relu(...)   MODE 1: part = relu(...)
// MODE 2: part += relu(...)         MODE 3: out = sigmoid(lw*(part+relu(...))/3 + lb)
template <int DBITS, int MODE>
__global__ void layer_pass_t(const uint2* __restrict__ tmp, const int* __restrict__ cBase,
                             const float* __restrict__ zd_in, const float* __restrict__ x,
                             const float* __restrict__ dinv, const float* __restrict__ W,
                             const float* __restrict__ V, const float* __restrict__ b,
                             float* __restrict__ zd_out, float* __restrict__ part,
                             const float* __restrict__ lin_w, const float* __restrict__ lin_b,
                             float* __restrict__ outp, int N) {
    constexpr int DB = 1 << DBITS;
    __shared__ float acc[DB];
    int bk = blockIdx.x, tid = threadIdx.x;
    for (int i = tid; i < DB; i += blockDim.x) acc[i] = 0.f;
    __syncthreads();
    long beg = cBase[bk], end = cBase[bk + 1];
    const ull* tp = (const ull*)tmp;
    for (long j = beg + tid; j < end; j += blockDim.x) {
        ull v = __builtin_nontemporal_load(tp + j);
        unsigned key = (unsigned)v;
        atomicAdd(&acc[key >> 20], __uint_as_float((unsigned)(v >> 32)) * zd_in[key & 0xFFFFF]);
    }
    __syncthreads();
    float Wv = W[0], Vv = V[0], bv = b[0];
    for (int q = tid; q < DB; q += blockDim.x) {
        int node = (bk << DBITS) + q;
        if (node >= N) continue;
        float di = dinv[node];
        float s = di * acc[q];
        float h = relu_(fmaf(Wv, s, fmaf(Vv, x[node], bv)));
        if (MODE == 0) {
            zd_out[node] = di * h;
        } else if (MODE == 1) {
            part[node] = h;
        } else if (MODE == 2) {
            part[node] += h;
        } else {
            float m = (part[node] + h) * (1.f / 3.f);
            float z = fmaf(lin_w[0], m, lin_b[0]);
            outp[node] = 1.f / (1.f + __expf(-z));
        }
    }
}

// =================== launch ===================

extern "C" void kernel_launch(void* const* d_in, const int* in_sizes, int n_in,
                              void* d_out, int out_size, void* d_ws, size_t ws_size,
                              hipStream_t stream) {
    const float* x      = (const float*)d_in[0];
    const int*   eidx   = (const int*)d_in[1];
    const float* w      = (const float*)d_in[2];
    const float* initW  = (const float*)d_in[3];
    const float* weight = (const float*)d_in[4];
    const float* rootW  = (const float*)d_in[5];
    const float* bias   = (const float*)d_in[6];
    const float* lin_w  = (const float*)d_in[7];
    const float* lin_b  = (const float*)d_in[8];
    float* outp = (float*)d_out;

    const int N = in_sizes[0];
    const int E = in_sizes[2];
    const int* row = eidx;
    const int* col = eidx + (size_t)E;

    const int nbA  = (N + SRC_BUCK - 1) >> SRC_BITS;   // src buckets (1024 nodes)
    const int nbB  = (N + DST_BUCK - 1) >> DST_BITS;   // dst buckets (4096 nodes)
    const int nbD  = nbA;                              // fallback dst buckets (1024 nodes)

    auto align16 = [](size_t v) { return (v + 15) & ~(size_t)15; };

    // ---- primary: src-sorted, 4096-node dst buckets ----
    {
        size_t off = 0;
        size_t tmpAOff  = off; off += align16((size_t)E * 8);
        size_t tmpBOff  = off; off += align16((size_t)E * 8);
        size_t zdA0Off  = off; off += align16((size_t)N * 4);
        size_t zdA1Off  = off; off += align16((size_t)N * 4);
        size_t zdA2Off  = off; off += align16((size_t)N * 4);
        size_t zdB0Off  = off; off += align16((size_t)N * 4);
        size_t zdB1Off  = off; off += align16((size_t)N * 4);
        size_t zdB2Off  = off; off += align16((size_t)N * 4);
        size_t dinvOff  = off; off += align16((size_t)N * 4);
        size_t xdOff    = off; off += align16((size_t)N * 4);   // also reused as `part`
        size_t bhAOff   = off; off += align16((size_t)NPB_A * nbA * 4);
        size_t bhBOff   = off; off += align16((size_t)NPB_B * nbB * 4);
        size_t totAOff  = off; off += align16((size_t)nbA * 4);
        size_t totBOff  = off; off += align16((size_t)nbB * 4);
        size_t cBAOff   = off; off += align16((size_t)(nbA + 1) * 4);
        size_t cBBOff   = off; off += align16((size_t)(nbB + 1) * 4);
        size_t needed = off;

        if (ws_size >= needed && nbA <= 1024 && nbB <= 1024 && N <= (1 << 20)) {
            char* wsb = (char*)d_ws;
            uint2* tmpA = (uint2*)(wsb + tmpAOff);
            uint2* tmpB = (uint2*)(wsb + tmpBOff);
            float* zdA[3] = {(float*)(wsb + zdA0Off), (float*)(wsb + zdA1Off), (float*)(wsb + zdA2Off)};
            float* zdB[3] = {(float*)(wsb + zdB0Off), (float*)(wsb + zdB1Off), (float*)(wsb + zdB2Off)};
            float* dinv = (float*)(wsb + dinvOff);
            float* xd   = (float*)(wsb + xdOff);
            float* part = xd;                              // xd dead after layer0
            int* bhA   = (int*)(wsb + bhAOff);
            int* bhB   = (int*)(wsb + bhBOff);
            int* totA  = (int*)(wsb + totAOff);
            int* totB  = (int*)(wsb + totBOff);
            int* cBA   = (int*)(wsb + cBAOff);
            int* cBB   = (int*)(wsb + cBBOff);

            // build: src partition
            histA_kernel<<<NPB_A, PBT, 0, stream>>>(row, bhA, E, nbA);
            colscan_kernel<NPB_A><<<nbA, NPB_A, 0, stream>>>(bhA, totA, nbA);
            excl_scan_kernel<<<1, 1024, 0, stream>>>(totA, cBA, nbA, E);
            partA_kernel<<<NPB_A, PBT, 0, stream>>>(row, col, w, cBA, bhA, tmpA, E, nbA);
            // build: dst partition (src order preserved)
            histB_kernel<<<NPB_B, PBT, 0, stream>>>(tmpA, bhB, E, nbB);
            colscan_kernel<NPB_B><<<nbB, NPB_B, 0, stream>>>(bhB, totB, nbB);
            excl_scan_kernel<<<1, 1024, 0, stream>>>(totB, cBB, nbB, E);
            partB_kernel<<<NPB_B, PBT, 0, stream>>>(tmpA, cBA, cBB, bhB, tmpB, E, nbA, nbB);

            // degrees + layers
            bucket_deg_t<DST_BITS><<<nbB, 1024, 0, stream>>>(tmpB, cBB, x, dinv, xd, N);
            layer0_t<DST_BITS><<<nbB, 1024, 0, stream>>>(tmpB, cBB, xd, x, dinv, initW,
                                                         rootW + 0 * KK, bias + 0 * KK,
                                                         zdA[0], zdA[1], zdA[2], N);
            for (int k = 0; k < KK; ++k)
                layer_pass_t<DST_BITS, 0><<<nbB, 1024, 0, stream>>>(
                    tmpB, cBB, zdA[k], x, dinv, weight + 0 * KK + k, rootW + 1 * KK + k,
                    bias + 1 * KK + k, zdB[k], nullptr, nullptr, nullptr, nullptr, N);
            for (int k = 0; k < KK; ++k)
                layer_pass_t<DST_BITS, 0><<<nbB, 1024, 0, stream>>>(
                    tmpB, cBB, zdB[k], x, dinv, weight + 1 * KK + k, rootW + 2 * KK + k,
                    bias + 2 * KK + k, zdA[k], nullptr, nullptr, nullptr, nullptr, N);
            layer_pass_t<DST_BITS, 1><<<nbB, 1024, 0, stream>>>(
                tmpB, cBB, zdA[0], x, dinv, weight + 2 * KK + 0, rootW + 3 * KK + 0,
                bias + 3 * KK + 0, nullptr, part, nullptr, nullptr, nullptr, N);
            layer_pass_t<DST_BITS, 2><<<nbB, 1024, 0, stream>>>(
                tmpB, cBB, zdA[1], x, dinv, weight + 2 * KK + 1, rootW + 3 * KK + 1,
                bias + 3 * KK + 1, nullptr, part, nullptr, nullptr, nullptr, N);
            layer_pass_t<DST_BITS, 3><<<nbB, 1024, 0, stream>>>(
                tmpB, cBB, zdA[2], x, dinv, weight + 2 * KK + 2, rootW + 3 * KK + 2,
                bias + 3 * KK + 2, nullptr, part, lin_w, lin_b, outp, N);
            return;
        }
    }

    // ---- fallback: direct dst partition, 1024-node buckets (round-6 structure, lean grid) ----
    {
        size_t off = 0;
        size_t tmpOff   = off; off += align16((size_t)E * 8);
        size_t zdA0Off  = off; off += align16((size_t)N * 4);
        size_t zdA1Off  = off; off += align16((size_t)N * 4);
        size_t zdA2Off  = off; off += align16((size_t)N * 4);
        size_t zdB0Off  = off; off += align16((size_t)N * 4);
        size_t zdB1Off  = off; off += align16((size_t)N * 4);
        size_t zdB2Off  = off; off += align16((size_t)N * 4);
        size_t dinvOff  = off; off += align16((size_t)N * 4);
        size_t xdOff    = off; off += align16((size_t)N * 4);
        size_t bhOff    = off; off += align16((size_t)NPB_A * nbD * 4);
        size_t totOff   = off; off += align16((size_t)nbD * 4);
        size_t cBOff    = off; off += align16((size_t)(nbD + 1) * 4);

        char* wsb = (char*)d_ws;
        uint2* tmp  = (uint2*)(wsb + tmpOff);
        float* zdA[3] = {(float*)(wsb + zdA0Off), (float*)(wsb + zdA1Off), (float*)(wsb + zdA2Off)};
        float* zdB[3] = {(float*)(wsb + zdB0Off), (float*)(wsb + zdB1Off), (float*)(wsb + zdB2Off)};
        float* dinv = (float*)(wsb + dinvOff);
        float* xd   = (float*)(wsb + xdOff);
        float* part = xd;
        int* bh   = (int*)(wsb + bhOff);
        int* tot  = (int*)(wsb + totOff);
        int* cB   = (int*)(wsb + cBOff);

        histD_kernel<<<NPB_A, PBT, 0, stream>>>(col, bh, E, nbD);
        colscan_kernel<NPB_A><<<nbD, NPB_A, 0, stream>>>(bh, tot, nbD);
        excl_scan_kernel<<<1, 1024, 0, stream>>>(tot, cB, nbD, E);
        partD_kernel<<<NPB_A, PBT, 0, stream>>>(row, col, w, cB, bh, tmp, E, nbD);

        bucket_deg_t<SRC_BITS><<<nbD, 1024, 0, stream>>>(tmp, cB, x, dinv, xd, N);
        layer0_t<SRC_BITS><<<nbD, 1024, 0, stream>>>(tmp, cB, xd, x, dinv, initW,
                                                     rootW + 0 * KK, bias + 0 * KK,
                                                     zdA[0], zdA[1], zdA[2], N);
        for (int k = 0; k < KK; ++k)
            layer_pass_t<SRC_BITS, 0><<<nbD, 1024, 0, stream>>>(
                tmp, cB, zdA[k], x, dinv, weight + 0 * KK + k, rootW + 1 * KK + k,
                bias + 1 * KK + k, zdB[k], nullptr, nullptr, nullptr, nullptr, N);
        for (int k = 0; k < KK; ++k)
            layer_pass_t<SRC_BITS, 0><<<nbD, 1024, 0, stream>>>(
                tmp, cB, zdB[k], x, dinv, weight + 1 * KK + k, rootW + 2 * KK + k,
                bias + 2 * KK + k, zdA[k], nullptr, nullptr, nullptr, nullptr, N);
        layer_pass_t<SRC_BITS, 1><<<nbD, 1024, 0, stream>>>(
            tmp, cB, zdA[0], x, dinv, weight + 2 * KK + 0, rootW + 3 * KK + 0,
            bias + 3 * KK + 0, nullptr, part, nullptr, nullptr, nullptr, N);
        layer_pass_t<SRC_BITS, 2><<<nbD, 1024, 0, stream>>>(
            tmp, cB, zdA[1], x, dinv, weight + 2 * KK + 1, rootW + 3 * KK + 1,
            bias + 3 * KK + 1, nullptr, part, nullptr, nullptr, nullptr, N);
        layer_pass_t<SRC_BITS, 3><<<nbD, 1024, 0, stream>>>(
            tmp, cB, zdA[2], x, dinv, weight + 2 * KK + 2, rootW + 3 * KK + 2,
            bias + 3 * KK + 2, nullptr, part, lin_w, lin_b, outp, N);
    }
}